// Round 8
// baseline (20.170 us; speedup 1.0000x reference)
//
#include <hip/hip_runtime.h>

// ---------------------------------------------------------------------------
// Quantum conv2d, packed-fp32, TWO PIXELS PER THREAD (ILP edition).
// Evidence: 2 waves/SIMD in lockstep can't hide VOP3P dependent latency
// (memory-latency theory falsified by round-6 pins). Each thread now carries
// two independent 16-dim states, manually interleaved op-by-op: dependent
// chains of pixel A hide under pixel B's issue and vice versa. Gate
// coefficients are shared between the two states. Channel loop kept rolled
// so the body stays I$-resident.
// ---------------------------------------------------------------------------

typedef float f2 __attribute__((ext_vector_type(2)));

__device__ __forceinline__ f2 pkfma(f2 a, f2 b, f2 c) {
    return __builtin_elementwise_fma(a, b, c);
}
__device__ __forceinline__ f2 swap2(f2 v) {
    return __builtin_shufflevector(v, v, 1, 0);
}
__device__ __forceinline__ void pin2(f2& v)   { asm volatile("" : "+v"(v)); }
__device__ __forceinline__ void pinf(float& v){ asm volatile("" : "+v"(v)); }

struct GateM { f2 m00rr, m00ni, m01rr, m01ni, m10rr, m10ni, m11rr, m11ni; };

__device__ __forceinline__ GateM load_gate(const float* gp) {
    const float4* p = (const float4*)gp;
    const float4 e0 = p[0], e1 = p[1], e2 = p[2], e3 = p[3];
    GateM G;
    G.m00rr = f2{e0.x, e0.y}; G.m00ni = f2{e0.z, e0.w};
    G.m01rr = f2{e1.x, e1.y}; G.m01ni = f2{e1.z, e1.w};
    G.m10rr = f2{e2.x, e2.y}; G.m10ni = f2{e2.z, e2.w};
    G.m11rr = f2{e3.x, e3.y}; G.m11ni = f2{e3.z, e3.w};
    return G;
}
__device__ __forceinline__ void pin_gate(GateM& G) {
    pin2(G.m00rr); pin2(G.m00ni); pin2(G.m01rr); pin2(G.m01ni);
    pin2(G.m10rr); pin2(G.m10ni); pin2(G.m11rr); pin2(G.m11ni);
}

// One 2x2 gate applied to BOTH states, interleaved instruction-by-instruction.
template<int STRIDE>
__device__ __forceinline__ void apply_gate2(f2* sA, f2* sB, const GateM G) {
    #pragma unroll
    for (int m0 = 0; m0 < 16; ++m0) {
        if (m0 & STRIDE) continue;
        const int m1 = m0 | STRIDE;
        const f2 aA = sA[m0], bA = sA[m1];
        const f2 aB = sB[m0], bB = sB[m1];
        const f2 asA = swap2(aA), bsA = swap2(bA);
        const f2 asB = swap2(aB), bsB = swap2(bB);
        f2 o0A = G.m00rr * aA;            f2 o0B = G.m00rr * aB;
        o0A = pkfma(G.m00ni, asA, o0A);   o0B = pkfma(G.m00ni, asB, o0B);
        o0A = pkfma(G.m01rr, bA,  o0A);   o0B = pkfma(G.m01rr, bB,  o0B);
        o0A = pkfma(G.m01ni, bsA, o0A);   o0B = pkfma(G.m01ni, bsB, o0B);
        f2 o1A = G.m10rr * aA;            f2 o1B = G.m10rr * aB;
        o1A = pkfma(G.m10ni, asA, o1A);   o1B = pkfma(G.m10ni, asB, o1B);
        o1A = pkfma(G.m11rr, bA,  o1A);   o1B = pkfma(G.m11rr, bB,  o1B);
        o1A = pkfma(G.m11ni, bsA, o1A);   o1B = pkfma(G.m11ni, bsB, o1B);
        sA[m0] = o0A; sA[m1] = o1A;
        sB[m0] = o0B; sB[m1] = o1B;
    }
}

template<int BC, int BT>
__device__ __forceinline__ void apply_cnot2(f2* sA, f2* sB) {
    #pragma unroll
    for (int m = 0; m < 16; ++m) {
        if ((m & BC) && !(m & BT)) {
            const int m2 = m | BT;
            f2 t;
            t = sA[m]; sA[m] = sA[m2]; sA[m2] = t;
            t = sB[m]; sB[m] = sB[m2]; sB[m2] = t;
        }
    }
}

struct Node { f2 cc, ss, ns; };

__device__ __forceinline__ Node node_cs(float lo, float hi) {
    const float den = lo + hi;
    const bool ok = den > 1e-30f;
    const float rs = __builtin_amdgcn_rsqf(fmaxf(den, 1e-37f));
    const float c = ok ? __builtin_amdgcn_sqrtf(lo) * rs : 1.0f;
    const float s = ok ? __builtin_amdgcn_sqrtf(hi) * rs : 0.0f;
    return Node{f2{c, c}, f2{s, s}, f2{-s, -s}};
}

template<int I0, int I1>
__device__ __forceinline__ void rot_pair2(f2* sA, const Node& nA,
                                          f2* sB, const Node& nB) {
    const f2 aA = sA[I0], bA = sA[I1];
    const f2 aB = sB[I0], bB = sB[I1];
    sA[I0] = pkfma(nA.cc, aA, nA.ns * bA);
    sB[I0] = pkfma(nB.cc, aB, nB.ns * bB);
    sA[I1] = pkfma(nA.ss, aA, nA.cc * bA);
    sB[I1] = pkfma(nB.ss, aB, nB.cc * bB);
}

struct NodeSet { Node n0, n1, n2a, n2b, n3a, n3b, n3c, n3d; };

__device__ __forceinline__ NodeSet make_nodes(const float* Q) {
    const float s01 = Q[0]+Q[1], s23 = Q[2]+Q[3];
    const float s45 = Q[4]+Q[5], s67 = Q[6]+Q[7];
    const float s03 = s01+s23, s47 = s45+s67, s07 = s03+s47;
    NodeSet N;
    N.n0  = node_cs(s07,  Q[8]);
    N.n1  = node_cs(s03,  s47);
    N.n2a = node_cs(s01,  s23);
    N.n2b = node_cs(s45,  s67);
    N.n3a = node_cs(Q[0], Q[1]);
    N.n3b = node_cs(Q[2], Q[3]);
    N.n3c = node_cs(Q[4], Q[5]);
    N.n3d = node_cs(Q[6], Q[7]);
    return N;
}

__device__ __forceinline__ void cascade2(f2* sA, const float* QA,
                                         f2* sB, const float* QB) {
    const NodeSet A = make_nodes(QA);
    const NodeSet B = make_nodes(QB);
    rot_pair2<0, 8>(sA, A.n0,  sB, B.n0);
    rot_pair2<1, 9>(sA, A.n0,  sB, B.n0);
    rot_pair2<2,10>(sA, A.n0,  sB, B.n0);
    rot_pair2<3,11>(sA, A.n0,  sB, B.n0);
    rot_pair2<4,12>(sA, A.n0,  sB, B.n0);
    rot_pair2<5,13>(sA, A.n0,  sB, B.n0);
    rot_pair2<6,14>(sA, A.n0,  sB, B.n0);
    rot_pair2<7,15>(sA, A.n0,  sB, B.n0);
    rot_pair2<0, 4>(sA, A.n1,  sB, B.n1);
    rot_pair2<1, 5>(sA, A.n1,  sB, B.n1);
    rot_pair2<2, 6>(sA, A.n1,  sB, B.n1);
    rot_pair2<3, 7>(sA, A.n1,  sB, B.n1);
    rot_pair2<0, 2>(sA, A.n2a, sB, B.n2a);
    rot_pair2<1, 3>(sA, A.n2a, sB, B.n2a);
    rot_pair2<4, 6>(sA, A.n2b, sB, B.n2b);
    rot_pair2<5, 7>(sA, A.n2b, sB, B.n2b);
    rot_pair2<0, 1>(sA, A.n3a, sB, B.n3a);
    rot_pair2<2, 3>(sA, A.n3b, sB, B.n3b);
    rot_pair2<4, 5>(sA, A.n3c, sB, B.n3c);
    rot_pair2<6, 7>(sA, A.n3d, sB, B.n3d);
}

__global__ __launch_bounds__(256, 1) void qconv_kernel(
        const float* __restrict__ x,     // (32, 4, 64, 64)
        const float* __restrict__ wts,   // (4, 2, 4, 3)
        float* __restrict__ out) {       // (32, 16, 64, 64)
    __shared__ float smat[32 * 16];      // packed gates {re,re,-im,im}
    __shared__ float tile[10 * 4 * 64];  // rows y0-1..y0+8, 4 channels

    const int tid = threadIdx.x;
    const int blk = blockIdx.x;          // 256 blocks
    const int b  = blk >> 3;             // image
    const int y0 = (blk & 7) << 3;       // first of 8 rows

    // --- build packed Rot matrices (one thread per gate) ---
    if (tid < 32) {
        const float phi   = wts[tid*3 + 0];
        const float theta = wts[tid*3 + 1];
        const float omega = wts[tid*3 + 2];
        float st, ct; __sincosf(0.5f * theta,         &st, &ct);
        float sA, cA; __sincosf(0.5f * (phi + omega), &sA, &cA);
        float sB, cB; __sincosf(0.5f * (phi - omega), &sB, &cB);
        float* g = &smat[tid * 16];
        g[0]  =  cA*ct; g[1]  =  cA*ct; g[2]  =  sA*ct; g[3]  = -sA*ct; // m00
        g[4]  = -cB*st; g[5]  = -cB*st; g[6]  =  sB*st; g[7]  = -sB*st; // m01
        g[8]  =  cB*st; g[9]  =  cB*st; g[10] =  sB*st; g[11] = -sB*st; // m10
        g[12] =  cA*ct; g[13] =  cA*ct; g[14] = -sA*ct; g[15] =  sA*ct; // m11
    }

    // --- stage input tile (coalesced), pad rows with 0.01 ---
    const float* xb = x + (size_t)b * 16384;
    #pragma unroll
    for (int i = 0; i < 10; ++i) {
        const int e = tid + i * 256;          // [r][ch][col], r in 0..9
        const int r = e >> 8, ch = (e >> 6) & 3, col = e & 63;
        const int gy = y0 - 1 + r;
        const int gyc = min(max(gy, 0), 63);
        float v = xb[ch * 4096 + gyc * 64 + col];
        v = ((unsigned)gy < 64u) ? v : 0.01f;
        tile[e] = v;
    }
    __syncthreads();

    const int ly = tid >> 6, xc = tid & 63;   // pixel A row y0+ly, B row +4
    const int colm = min(max(xc - 1, 0), 63);
    const int colp = min(xc + 1, 63);
    const bool inm = xc > 0, inp = xc < 63;

    f2 sA[16], sB[16];
    #pragma unroll
    for (int i = 0; i < 16; ++i) { sA[i] = f2{0.f, 0.f}; sB[i] = f2{0.f, 0.f}; }
    sA[0] = f2{1.f, 0.f}; sB[0] = f2{1.f, 0.f};

    #pragma unroll 1
    for (int ic = 0; ic < 4; ++ic) {
        // ---- issue both pixels' patch loads (batched) ----
        float pA[9], pB[9];
        #pragma unroll
        for (int dy = 0; dy < 3; ++dy) {
            const float* rowA = tile + ((ly     + dy) * 4 + ic) * 64;
            const float* rowB = tile + ((ly + 4 + dy) * 4 + ic) * 64;
            pA[dy*3 + 0] = rowA[colm]; pB[dy*3 + 0] = rowB[colm];
            pA[dy*3 + 1] = rowA[xc];   pB[dy*3 + 1] = rowB[xc];
            pA[dy*3 + 2] = rowA[colp]; pB[dy*3 + 2] = rowB[colp];
        }
        // ---- issue gate loads (shared by both pixels, stay in flight) ----
        GateM g[8];
        const float* cb = smat + ic * 128;
        #pragma unroll
        for (int i = 0; i < 8; ++i) g[i] = load_gate(cb + i * 16);

        #pragma unroll
        for (int j = 0; j < 9; ++j) { pinf(pA[j]); pinf(pB[j]); }

        float qA[9], qB[9];
        #pragma unroll
        for (int dy = 0; dy < 3; ++dy) {
            float vmA = inm ? pA[dy*3+0] : 0.01f;
            float vmB = inm ? pB[dy*3+0] : 0.01f;
            float v0A = pA[dy*3+1],   v0B = pB[dy*3+1];
            float vpA = inp ? pA[dy*3+2] : 0.01f;
            float vpB = inp ? pB[dy*3+2] : 0.01f;
            qA[dy*3+0] = vmA*vmA;  qB[dy*3+0] = vmB*vmB;
            qA[dy*3+1] = v0A*v0A;  qB[dy*3+1] = v0B*v0B;
            qA[dy*3+2] = vpA*vpA;  qB[dy*3+2] = vpB*vpB;
        }

        cascade2(sA, qA, sB, qB);        // gate loads still in flight

        #pragma unroll
        for (int i = 0; i < 8; ++i) pin_gate(g[i]);

        apply_gate2<8>(sA, sB, g[0]);
        apply_gate2<4>(sA, sB, g[1]);
        apply_gate2<2>(sA, sB, g[2]);
        apply_gate2<1>(sA, sB, g[3]);
        apply_cnot2<8, 4>(sA, sB); apply_cnot2<4, 2>(sA, sB);
        apply_cnot2<2, 1>(sA, sB); apply_cnot2<1, 8>(sA, sB);
        apply_gate2<8>(sA, sB, g[4]);
        apply_gate2<4>(sA, sB, g[5]);
        apply_gate2<2>(sA, sB, g[6]);
        apply_gate2<1>(sA, sB, g[7]);
        apply_cnot2<8, 2>(sA, sB); apply_cnot2<4, 1>(sA, sB);
        apply_cnot2<2, 8>(sA, sB); apply_cnot2<1, 4>(sA, sB);
    }

    // --- probabilities -> clipped output, (b, 16, 64, 64) ---
    float* obA = out + (size_t)b * (16 * 4096) + (y0 + ly) * 64 + xc;
    #pragma unroll
    for (int m = 0; m < 16; ++m) {
        const float prA = sA[m].x * sA[m].x + sA[m].y * sA[m].y;
        const float prB = sB[m].x * sB[m].x + sB[m].y * sB[m].y;
        obA[m * 4096]       = fminf(prA * 8.0f, 1.0f);
        obA[m * 4096 + 256] = fminf(prB * 8.0f, 1.0f);   // row +4
    }
}

extern "C" void kernel_launch(void* const* d_in, const int* in_sizes, int n_in,
                              void* d_out, int out_size, void* d_ws, size_t ws_size,
                              hipStream_t stream) {
    const float* x   = (const float*)d_in[0];
    const float* wts = (const float*)d_in[1];
    float* out = (float*)d_out;
    // 131072 pixels, 2 per thread: 256 blocks x 256 threads
    qconv_kernel<<<256, 256, 0, stream>>>(x, wts, out);
}

// Round 9
// 17.857 us; speedup vs baseline: 1.1295x; 1.1295x over previous
//
#include <hip/hip_runtime.h>

// ---------------------------------------------------------------------------
// Quantum conv2d, MFMA edition.
// Per channel: data-dependent Mottonen cascade (VALU) + fixed 16x16 complex
// unitary U_ic (all 8 Rot gates + both CNOT rings fused) applied as a real
// 32x32 matrix via 2x v_mfma_f32_32x32x16_f16 (fp32 accumulate).
// State lives in the MFMA C/D layout across 2 lanes per pixel:
//   col = lane&31 (pixel), row = (reg&3)+8*(reg>>2)+4*(lane>>5),
//   rows 0-15 = Re(amp), 16-31 = Im(amp).
// A/B fragments are packed with ONE shared k-convention (k = 8*hi + i), so
// any hardware k-permutation cancels between A(U) and B(state).
// ---------------------------------------------------------------------------

typedef float     f2      __attribute__((ext_vector_type(2)));
typedef _Float16  half8_t __attribute__((ext_vector_type(8)));
typedef float     f32x16  __attribute__((ext_vector_type(16)));

// ---------- f2 complex helpers (setup phase: evolve U columns) ----------
__device__ __forceinline__ f2 pkfma(f2 a, f2 b, f2 c) {
    return __builtin_elementwise_fma(a, b, c);
}
__device__ __forceinline__ f2 swap2(f2 v) {
    return __builtin_shufflevector(v, v, 1, 0);
}

struct GateM { f2 m00rr, m00ni, m01rr, m01ni, m10rr, m10ni, m11rr, m11ni; };

__device__ __forceinline__ GateM load_gate(const float* gp) {
    const float4* p = (const float4*)gp;
    const float4 e0 = p[0], e1 = p[1], e2 = p[2], e3 = p[3];
    GateM G;
    G.m00rr = f2{e0.x, e0.y}; G.m00ni = f2{e0.z, e0.w};
    G.m01rr = f2{e1.x, e1.y}; G.m01ni = f2{e1.z, e1.w};
    G.m10rr = f2{e2.x, e2.y}; G.m10ni = f2{e2.z, e2.w};
    G.m11rr = f2{e3.x, e3.y}; G.m11ni = f2{e3.z, e3.w};
    return G;
}

template<int STRIDE>
__device__ __forceinline__ void apply_gate(f2* s, const GateM G) {
    #pragma unroll
    for (int m0 = 0; m0 < 16; ++m0) {
        if (m0 & STRIDE) continue;
        const int m1 = m0 | STRIDE;
        const f2 a = s[m0], b = s[m1];
        const f2 as = swap2(a), bs = swap2(b);
        f2 o0 = G.m00rr * a;
        o0 = pkfma(G.m00ni, as, o0);
        o0 = pkfma(G.m01rr, b,  o0);
        o0 = pkfma(G.m01ni, bs, o0);
        f2 o1 = G.m10rr * a;
        o1 = pkfma(G.m10ni, as, o1);
        o1 = pkfma(G.m11rr, b,  o1);
        o1 = pkfma(G.m11ni, bs, o1);
        s[m0] = o0; s[m1] = o1;
    }
}

template<int BC, int BT>
__device__ __forceinline__ void apply_cnot(f2* s) {
    #pragma unroll
    for (int m = 0; m < 16; ++m) {
        if ((m & BC) && !(m & BT)) {
            const int m2 = m | BT;
            const f2 t = s[m]; s[m] = s[m2]; s[m2] = t;
        }
    }
}

// Multiplexed-RY node from un-normalized child sums (scale cancels).
__device__ __forceinline__ void node_cs(float lo, float hi_, float& c, float& s) {
    const float den = lo + hi_;
    const bool ok = den > 1e-30f;
    const float rs = __builtin_amdgcn_rsqf(fmaxf(den, 1e-37f));
    c = ok ? __builtin_amdgcn_sqrtf(lo)  * rs : 1.0f;
    s = ok ? __builtin_amdgcn_sqrtf(hi_) * rs : 0.0f;
}

#define ROTP(a, b, c, s) { \
    const float _na = fmaf((c), (a), -((s) * (b))); \
    const float _nb = fmaf((s), (a),  ((c) * (b))); \
    (a) = _na; (b) = _nb; }

__global__ __launch_bounds__(256) void qconv_kernel(
        const float* __restrict__ x,     // (32, 4, 64, 64)
        const float* __restrict__ wts,   // (4, 2, 4, 3)
        float* __restrict__ out) {       // (32, 16, 64, 64)
    __shared__ float   smat[32 * 16];    // 2 KB packed gate coeffs
    __shared__ float   tile[4 * 4 * 64]; // 4 KB input rows 2ry-1..2ry+2
    __shared__ f2      ucol[4 * 16 * 16];// 8 KB U columns (complex f32)
    __shared__ half8_t ufrag[4 * 64 * 2];// 8 KB A-fragments (f16)

    const int tid = threadIdx.x;
    const int blk = blockIdx.x;          // 1024 blocks
    const int b  = blk >> 5;             // image
    const int ry = blk & 31;             // rows 2ry, 2ry+1

    // --- stage input tile (coalesced), pad with 0.01 ---
    const float* xb = x + (size_t)b * 16384;
    #pragma unroll
    for (int i = 0; i < 4; ++i) {
        const int e = tid + i * 256;     // [r][ch][col], r=0..3
        const int r = e >> 8, ch = (e >> 6) & 3, col = e & 63;
        const int gy = 2 * ry - 1 + r;
        const int gyc = min(max(gy, 0), 63);
        float val = xb[ch * 4096 + gyc * 64 + col];
        val = ((unsigned)gy < 64u) ? val : 0.01f;
        tile[e] = val;
    }

    // --- build packed Rot matrices (one thread per gate) ---
    if (tid < 32) {
        const float phi   = wts[tid*3 + 0];
        const float theta = wts[tid*3 + 1];
        const float omega = wts[tid*3 + 2];
        float st, ct; __sincosf(0.5f * theta,         &st, &ct);
        float sA, cA; __sincosf(0.5f * (phi + omega), &sA, &cA);
        float sB, cB; __sincosf(0.5f * (phi - omega), &sB, &cB);
        float* g = &smat[tid * 16];
        g[0]  =  cA*ct; g[1]  =  cA*ct; g[2]  =  sA*ct; g[3]  = -sA*ct; // m00
        g[4]  = -cB*st; g[5]  = -cB*st; g[6]  =  sB*st; g[7]  = -sB*st; // m01
        g[8]  =  cB*st; g[9]  =  cB*st; g[10] =  sB*st; g[11] = -sB*st; // m10
        g[12] =  cA*ct; g[13] =  cA*ct; g[14] = -sA*ct; g[15] =  sA*ct; // m11
    }
    __syncthreads();

    // --- evolve U columns: thread t<64 owns (ch = t>>4, col = t&15) ---
    if (tid < 64) {
        const int ch = tid >> 4, col = tid & 15;
        f2 u[16];
        #pragma unroll
        for (int j = 0; j < 16; ++j)
            u[j] = (j == col) ? f2{1.f, 0.f} : f2{0.f, 0.f};
        const float* cb = smat + ch * 128;
        apply_gate<8>(u, load_gate(cb + 0*16));
        apply_gate<4>(u, load_gate(cb + 1*16));
        apply_gate<2>(u, load_gate(cb + 2*16));
        apply_gate<1>(u, load_gate(cb + 3*16));
        apply_cnot<8, 4>(u); apply_cnot<4, 2>(u);
        apply_cnot<2, 1>(u); apply_cnot<1, 8>(u);
        apply_gate<8>(u, load_gate(cb + 4*16));
        apply_gate<4>(u, load_gate(cb + 5*16));
        apply_gate<2>(u, load_gate(cb + 6*16));
        apply_gate<1>(u, load_gate(cb + 7*16));
        apply_cnot<8, 2>(u); apply_cnot<4, 1>(u);
        apply_cnot<2, 8>(u); apply_cnot<1, 4>(u);
        #pragma unroll
        for (int j = 0; j < 16; ++j)
            ucol[(ch * 16 + col) * 16 + j] = u[j];
    }
    __syncthreads();

    // --- build A-fragments: t = (ch = t>>6, l = t&63) ---
    {
        const int ch = tid >> 6, l = tid & 63;
        const int m = l & 31, hif = l >> 5;
        const bool mi = m >= 16;
        const int mr = m & 15;
        #pragma unroll
        for (int ks = 0; ks < 2; ++ks) {
            half8_t f;
            #pragma unroll
            for (int i = 0; i < 8; ++i) {
                const int k = ks * 16 + hif * 8 + i; // shared k-convention
                const int kc = k & 15;
                const bool ki = k >= 16;
                const f2 e = ucol[(ch * 16 + kc) * 16 + mr];
                // real-stacked U: m<16: [Ur | -Ui], m>=16: [Ui | Ur]
                const float val = mi ? (ki ? e.x : e.y) : (ki ? -e.y : e.x);
                f[i] = (_Float16)val;
            }
            ufrag[(ch * 64 + l) * 2 + ks] = f;
        }
    }
    __syncthreads();

    // --- main: wave w (0-3) -> row 2ry+(w>>1), cols 32*(w&1)+..; 2 lanes/px ---
    const int w = tid >> 6, lane = tid & 63;
    const int hi = lane >> 5;                 // which half of rows this lane owns
    const int row = 2 * ry + (w >> 1);
    const int xc = ((w & 1) << 5) + (lane & 31);
    const int colm = min(max(xc - 1, 0), 63);
    const int colp = min(xc + 1, 63);
    const bool inm = xc > 0, inp = xc < 63;
    const int tr0 = (w >> 1);                 // tile row base for dy=0

    // state regs: v[0-3]=Re(amp 4hi+k), v[4-7]=Re(amp 8+4hi+k),
    //             v[8-11]=Im(amp 4hi+k), v[12-15]=Im(amp 8+4hi+k)
    float v[16];
    #pragma unroll
    for (int i = 0; i < 16; ++i) v[i] = 0.f;
    v[0] = hi ? 0.f : 1.f;                    // |0> : Re(amp0)=1 on lanes<32

    #pragma unroll
    for (int ic = 0; ic < 4; ++ic) {
        // ---- squared 3x3 patch ----
        float q[9];
        #pragma unroll
        for (int dy = 0; dy < 3; ++dy) {
            const float* rowp = tile + ((tr0 + dy) * 4 + ic) * 64;
            float vm = rowp[colm]; vm = inm ? vm : 0.01f;
            float v0 = rowp[xc];
            float vp = rowp[colp]; vp = inp ? vp : 0.01f;
            q[dy*3 + 0] = vm * vm;
            q[dy*3 + 1] = v0 * v0;
            q[dy*3 + 2] = vp * vp;
        }

        // ---- Mottonen nodes ----
        const float s01 = q[0]+q[1], s23 = q[2]+q[3];
        const float s45 = q[4]+q[5], s67 = q[6]+q[7];
        const float s03 = s01+s23, s47 = s45+s67, s07 = s03+s47;
        float c0,s0,c1,s1,c2a,s2a,c2b,s2b,c3a,s3a,c3b,s3b,c3c,s3c,c3d,s3d;
        node_cs(s07,  q[8], c0,  s0);
        node_cs(s03,  s47,  c1,  s1);
        node_cs(s01,  s23,  c2a, s2a);
        node_cs(s45,  s67,  c2b, s2b);
        node_cs(q[0], q[1], c3a, s3a);
        node_cs(q[2], q[3], c3b, s3b);
        node_cs(q[4], q[5], c3c, s3c);
        node_cs(q[6], q[7], c3d, s3d);
        // per-lane-half effective coefficients
        const float c2e = hi ? c2b : c2a, s2e = hi ? s2b : s2a;
        const float c3x = hi ? c3c : c3a, s3x = hi ? s3c : s3a;
        const float c3y = hi ? c3d : c3b, s3y = hi ? s3d : s3b;
        const float bs1 = hi ? s1 : -s1;

        // ---- cascade on C/D-layout state ----
        // t0: amps (j, j+8) -> regs (k, k+4) re and (k+8, k+12) im, node n0
        #pragma unroll
        for (int k = 0; k < 4; ++k) {
            ROTP(v[k],     v[k+4],  c0, s0);
            ROTP(v[k+8],   v[k+12], c0, s0);
        }
        // t1: amps (j, j+4) cross-lane (xor32) on regs 0-3 (re) & 8-11 (im)
        #pragma unroll
        for (int k = 0; k < 4; ++k) {
            const float rr = __shfl_xor(v[k], 32);
            const float ri = __shfl_xor(v[8+k], 32);
            v[k]   = fmaf(c1, v[k],   bs1 * rr);
            v[8+k] = fmaf(c1, v[8+k], bs1 * ri);
        }
        // t2: local pairs (0,2),(1,3) re & im, node n2a/n2b by half
        ROTP(v[0], v[2],  c2e, s2e);  ROTP(v[1], v[3],  c2e, s2e);
        ROTP(v[8], v[10], c2e, s2e);  ROTP(v[9], v[11], c2e, s2e);
        // t3: local pairs (0,1),(2,3) re & im, nodes n3a..d by half
        ROTP(v[0], v[1],  c3x, s3x);  ROTP(v[2], v[3],  c3y, s3y);
        ROTP(v[8], v[9],  c3x, s3x);  ROTP(v[10], v[11], c3y, s3y);

        // ---- pack B fragments (same k-convention as ufrag) ----
        half8_t B0, B1;
        #pragma unroll
        for (int k = 0; k < 4; ++k) {
            // k-step 0 (Re rows 0-15): hi0 sends re amps 8-11, hi1 sends re 4-7
            const float snd = hi ? v[k] : v[4+k];
            const float rcv = __shfl_xor(snd, 32);
            B0[k]   = (_Float16)(hi ? rcv    : v[k]);    // hi0: amps0-3; hi1: 8-11
            B0[4+k] = (_Float16)(hi ? v[4+k] : rcv);     // hi0: amps4-7; hi1: 12-15
            // k-step 1 (Im rows 16-31)
            const float snd2 = hi ? v[8+k] : v[12+k];
            const float rcv2 = __shfl_xor(snd2, 32);
            B1[k]   = (_Float16)(hi ? rcv2    : v[8+k]);
            B1[4+k] = (_Float16)(hi ? v[12+k] : rcv2);
        }

        // ---- U apply: 2 chained MFMAs (K=32), fp32 accumulate ----
        const half8_t A0 = ufrag[(ic * 64 + lane) * 2 + 0];
        const half8_t A1 = ufrag[(ic * 64 + lane) * 2 + 1];
        f32x16 acc;
        #pragma unroll
        for (int i = 0; i < 16; ++i) acc[i] = 0.f;
        acc = __builtin_amdgcn_mfma_f32_32x32x16_f16(A0, B0, acc, 0, 0, 0);
        acc = __builtin_amdgcn_mfma_f32_32x32x16_f16(A1, B1, acc, 0, 0, 0);
        #pragma unroll
        for (int i = 0; i < 16; ++i) v[i] = acc[i];
    }

    // ---- probabilities -> clipped output, (b, 16, 64, 64) ----
    float* ob = out + (size_t)b * 65536 + (size_t)row * 64 + xc;
    #pragma unroll
    for (int k = 0; k < 4; ++k) {
        const float plo = v[k]   * v[k]   + v[8+k]  * v[8+k];   // amp 4hi+k
        const float phi = v[4+k] * v[4+k] + v[12+k] * v[12+k];  // amp 8+4hi+k
        ob[(4*hi + k) * 4096]       = fminf(plo * 8.f, 1.f);
        ob[(8 + 4*hi + k) * 4096]   = fminf(phi * 8.f, 1.f);
    }
}

extern "C" void kernel_launch(void* const* d_in, const int* in_sizes, int n_in,
                              void* d_out, int out_size, void* d_ws, size_t ws_size,
                              hipStream_t stream) {
    const float* x   = (const float*)d_in[0];
    const float* wts = (const float*)d_in[1];
    float* out = (float*)d_out;
    // 131072 pixels, 2 lanes each: 1024 blocks x 256 threads
    qconv_kernel<<<1024, 256, 0, stream>>>(x, wts, out);
}

// Round 11
// 16.447 us; speedup vs baseline: 1.2263x; 1.0857x over previous
//
#include <hip/hip_runtime.h>

// ---------------------------------------------------------------------------
// Quantum conv2d, MFMA edition v2 (type-fixed).
// Per channel: data-dependent Mottonen cascade (VALU) + fixed 16x16 complex
// unitary U_ic (8 Rot gates + 2 CNOT rings fused) applied as a real 32x32
// matrix via 2x v_mfma_f32_32x32x16_f16 (fp32 accumulate).
// State lives in the MFMA C/D layout, 2 lanes per pixel (col = lane&31):
//   lane half h owns amps {4h..4h+3, 8+4h..8+4h+3} (re and im).
// k-slot convention for BOTH A and B fragments: amp = 4*hif + (i&3) + 8*(i>>2)
// == exactly the amps each lane owns -> B-pack needs ZERO cross-lane ops
// (validated in R8: consistent A/B slot maps cancel the HW k-wiring).
// ---------------------------------------------------------------------------

typedef float     f2      __attribute__((ext_vector_type(2)));
typedef __fp16    fp16x2  __attribute__((ext_vector_type(2)));
typedef _Float16  half8_t __attribute__((ext_vector_type(8)));
typedef float     f32x16  __attribute__((ext_vector_type(16)));

union H8 { fp16x2 h2[4]; half8_t h8; };

// ---------- f2 complex helpers (setup phase: evolve U columns) ----------
__device__ __forceinline__ f2 pkfma(f2 a, f2 b, f2 c) {
    return __builtin_elementwise_fma(a, b, c);
}
__device__ __forceinline__ f2 swap2(f2 v) {
    return __builtin_shufflevector(v, v, 1, 0);
}

struct GateM { f2 m00rr, m00ni, m01rr, m01ni, m10rr, m10ni, m11rr, m11ni; };

__device__ __forceinline__ GateM load_gate(const float* gp) {
    const float4* p = (const float4*)gp;
    const float4 e0 = p[0], e1 = p[1], e2 = p[2], e3 = p[3];
    GateM G;
    G.m00rr = f2{e0.x, e0.y}; G.m00ni = f2{e0.z, e0.w};
    G.m01rr = f2{e1.x, e1.y}; G.m01ni = f2{e1.z, e1.w};
    G.m10rr = f2{e2.x, e2.y}; G.m10ni = f2{e2.z, e2.w};
    G.m11rr = f2{e3.x, e3.y}; G.m11ni = f2{e3.z, e3.w};
    return G;
}

template<int STRIDE>
__device__ __forceinline__ void apply_gate(f2* s, const GateM G) {
    #pragma unroll
    for (int m0 = 0; m0 < 16; ++m0) {
        if (m0 & STRIDE) continue;
        const int m1 = m0 | STRIDE;
        const f2 a = s[m0], b = s[m1];
        const f2 as = swap2(a), bs = swap2(b);
        f2 o0 = G.m00rr * a;
        o0 = pkfma(G.m00ni, as, o0);
        o0 = pkfma(G.m01rr, b,  o0);
        o0 = pkfma(G.m01ni, bs, o0);
        f2 o1 = G.m10rr * a;
        o1 = pkfma(G.m10ni, as, o1);
        o1 = pkfma(G.m11rr, b,  o1);
        o1 = pkfma(G.m11ni, bs, o1);
        s[m0] = o0; s[m1] = o1;
    }
}

template<int BC, int BT>
__device__ __forceinline__ void apply_cnot(f2* s) {
    #pragma unroll
    for (int m = 0; m < 16; ++m) {
        if ((m & BC) && !(m & BT)) {
            const int m2 = m | BT;
            const f2 t = s[m]; s[m] = s[m2]; s[m2] = t;
        }
    }
}

// Multiplexed-RY node from un-normalized child sums (scale cancels).
__device__ __forceinline__ void node_cs(float lo, float hi_, float& c, float& s) {
    const float den = lo + hi_;
    const bool ok = den > 1e-30f;
    const float rs = __builtin_amdgcn_rsqf(fmaxf(den, 1e-37f));
    c = ok ? __builtin_amdgcn_sqrtf(lo)  * rs : 1.0f;
    s = ok ? __builtin_amdgcn_sqrtf(hi_) * rs : 0.0f;
}

#define ROTP(a, b, c, s) { \
    const float _na = fmaf((c), (a), -((s) * (b))); \
    const float _nb = fmaf((s), (a),  ((c) * (b))); \
    (a) = _na; (b) = _nb; }

__global__ __launch_bounds__(256, 4) void qconv_kernel(
        const float* __restrict__ x,     // (32, 4, 64, 64)
        const float* __restrict__ wts,   // (4, 2, 4, 3)
        float* __restrict__ out) {       // (32, 16, 64, 64)
    __shared__ float   smat[32 * 16];    // 2 KB packed gate coeffs
    __shared__ float   tile[4 * 4 * 64]; // 4 KB input rows 2ry-1..2ry+2
    __shared__ f2      ucol[4 * 16 * 16];// 8 KB U columns (complex f32)
    __shared__ half8_t ufrag[4 * 2 * 64];// 4 KB A-fragments [ch][ks][lane]

    const int tid = threadIdx.x;
    const int blk = blockIdx.x;          // 1024 blocks
    const int b  = blk >> 5;             // image
    const int ry = blk & 31;             // rows 2ry, 2ry+1

    // --- stage input tile (coalesced), pad with 0.01 ---
    const float* xb = x + (size_t)b * 16384;
    #pragma unroll
    for (int i = 0; i < 4; ++i) {
        const int e = tid + i * 256;     // [r][ch][col], r=0..3
        const int r = e >> 8, ch = (e >> 6) & 3, col = e & 63;
        const int gy = 2 * ry - 1 + r;
        const int gyc = min(max(gy, 0), 63);
        float val = xb[ch * 4096 + gyc * 64 + col];
        val = ((unsigned)gy < 64u) ? val : 0.01f;
        tile[e] = val;
    }

    // --- build packed Rot matrices (one thread per gate) ---
    if (tid < 32) {
        const float phi   = wts[tid*3 + 0];
        const float theta = wts[tid*3 + 1];
        const float omega = wts[tid*3 + 2];
        float st, ct; __sincosf(0.5f * theta,         &st, &ct);
        float sA, cA; __sincosf(0.5f * (phi + omega), &sA, &cA);
        float sB, cB; __sincosf(0.5f * (phi - omega), &sB, &cB);
        float* g = &smat[tid * 16];
        g[0]  =  cA*ct; g[1]  =  cA*ct; g[2]  =  sA*ct; g[3]  = -sA*ct; // m00
        g[4]  = -cB*st; g[5]  = -cB*st; g[6]  =  sB*st; g[7]  = -sB*st; // m01
        g[8]  =  cB*st; g[9]  =  cB*st; g[10] =  sB*st; g[11] = -sB*st; // m10
        g[12] =  cA*ct; g[13] =  cA*ct; g[14] = -sA*ct; g[15] =  sA*ct; // m11
    }
    __syncthreads();

    // --- evolve U columns: thread t<64 owns (ch = t>>4, col = t&15) ---
    if (tid < 64) {
        const int ch = tid >> 4, col = tid & 15;
        f2 u[16];
        #pragma unroll
        for (int j = 0; j < 16; ++j)
            u[j] = (j == col) ? f2{1.f, 0.f} : f2{0.f, 0.f};
        const float* cb = smat + ch * 128;
        apply_gate<8>(u, load_gate(cb + 0*16));
        apply_gate<4>(u, load_gate(cb + 1*16));
        apply_gate<2>(u, load_gate(cb + 2*16));
        apply_gate<1>(u, load_gate(cb + 3*16));
        apply_cnot<8, 4>(u); apply_cnot<4, 2>(u);
        apply_cnot<2, 1>(u); apply_cnot<1, 8>(u);
        apply_gate<8>(u, load_gate(cb + 4*16));
        apply_gate<4>(u, load_gate(cb + 5*16));
        apply_gate<2>(u, load_gate(cb + 6*16));
        apply_gate<1>(u, load_gate(cb + 7*16));
        apply_cnot<8, 2>(u); apply_cnot<4, 1>(u);
        apply_cnot<2, 8>(u); apply_cnot<1, 4>(u);
        #pragma unroll
        for (int j = 0; j < 16; ++j)
            ucol[(ch * 16 + col) * 16 + j] = u[j];
    }
    __syncthreads();

    // --- build A-fragments: t = (ch = t>>6, l = t&63), layout [ch][ks][lane] ---
    {
        const int ch = tid >> 6, l = tid & 63;
        const int m = l & 31, hif = l >> 5;
        const bool mi = m >= 16;
        const int mr = m & 15;
        #pragma unroll
        for (int ks = 0; ks < 2; ++ks) {
            half8_t f;
            #pragma unroll
            for (int i = 0; i < 8; ++i) {
                // shared slot->amp convention (matches B-pack below)
                const int amp = 4 * hif + (i & 3) + 8 * (i >> 2);
                const f2 e = ucol[(ch * 16 + amp) * 16 + mr];
                // real-stacked U: m<16: [Ur | -Ui], m>=16: [Ui | Ur]; ks = Re/Im input
                const float val = mi ? (ks ? e.x : e.y) : (ks ? -e.y : e.x);
                f[i] = (_Float16)val;
            }
            ufrag[(ch * 2 + ks) * 64 + l] = f;
        }
    }
    __syncthreads();

    // --- main: wave w (0-3) -> row 2ry+(w>>1), cols 32*(w&1)+..; 2 lanes/px ---
    const int w = tid >> 6, lane = tid & 63;
    const int hi = lane >> 5;                 // which half of amps this lane owns
    const int row = 2 * ry + (w >> 1);
    const int xc = ((w & 1) << 5) + (lane & 31);
    const int colm = min(max(xc - 1, 0), 63);
    const int colp = min(xc + 1, 63);
    const bool inm = xc > 0, inp = xc < 63;
    const int tr0 = (w >> 1);                 // tile row base for dy=0

    // state regs: v[0-3]=Re(amp 4hi+k), v[4-7]=Re(amp 8+4hi+k),
    //             v[8-11]=Im(amp 4hi+k), v[12-15]=Im(amp 8+4hi+k)
    float v[16];
    #pragma unroll
    for (int i = 0; i < 16; ++i) v[i] = 0.f;
    v[0] = hi ? 0.f : 1.f;                    // |0> : Re(amp0)=1 on lanes<32

    #pragma unroll
    for (int ic = 0; ic < 4; ++ic) {
        // ---- A fragments first: ds_read_b128 latency hides under cascade ----
        const half8_t A0 = ufrag[(ic * 2 + 0) * 64 + lane];
        const half8_t A1 = ufrag[(ic * 2 + 1) * 64 + lane];

        // ---- squared 3x3 patch ----
        float q[9];
        #pragma unroll
        for (int dy = 0; dy < 3; ++dy) {
            const float* rowp = tile + ((tr0 + dy) * 4 + ic) * 64;
            float vm = rowp[colm]; vm = inm ? vm : 0.01f;
            float v0 = rowp[xc];
            float vp = rowp[colp]; vp = inp ? vp : 0.01f;
            q[dy*3 + 0] = vm * vm;
            q[dy*3 + 1] = v0 * v0;
            q[dy*3 + 2] = vp * vp;
        }

        // ---- Mottonen nodes: only the 5 this lane-half needs ----
        const float s01 = q[0]+q[1], s23 = q[2]+q[3];
        const float s45 = q[4]+q[5], s67 = q[6]+q[7];
        const float s03 = s01+s23, s47 = s45+s67, s07 = s03+s47;
        // per-half input selection (8 cndmask), then 5 node_cs (15 trans)
        const float i2lo = hi ? s45  : s01,  i2hi = hi ? s67  : s23;
        const float i3xl = hi ? q[4] : q[0], i3xh = hi ? q[5] : q[1];
        const float i3yl = hi ? q[6] : q[2], i3yh = hi ? q[7] : q[3];
        float c0,s0,c1,s1,c2e,s2e,c3x,s3x,c3y,s3y;
        node_cs(s07,  q[8], c0,  s0);
        node_cs(s03,  s47,  c1,  s1);
        node_cs(i2lo, i2hi, c2e, s2e);
        node_cs(i3xl, i3xh, c3x, s3x);
        node_cs(i3yl, i3yh, c3y, s3y);
        const float bs1 = hi ? s1 : -s1;

        // ---- cascade on C/D-layout state ----
        // t0: amps (j, j+8) -> regs (k, k+4) re and (k+8, k+12) im
        #pragma unroll
        for (int k = 0; k < 4; ++k) {
            ROTP(v[k],   v[k+4],  c0, s0);
            ROTP(v[k+8], v[k+12], c0, s0);
        }
        // t1: amps (j, j+4) cross-lane (xor32); batch shfls, then apply
        float rr[4], ri[4];
        #pragma unroll
        for (int k = 0; k < 4; ++k) rr[k] = __shfl_xor(v[k],   32);
        #pragma unroll
        for (int k = 0; k < 4; ++k) ri[k] = __shfl_xor(v[8+k], 32);
        #pragma unroll
        for (int k = 0; k < 4; ++k) {
            v[k]   = fmaf(c1, v[k],   bs1 * rr[k]);
            v[8+k] = fmaf(c1, v[8+k], bs1 * ri[k]);
        }
        // t2: local pairs (0,2),(1,3) re & im
        ROTP(v[0], v[2],  c2e, s2e);  ROTP(v[1], v[3],  c2e, s2e);
        ROTP(v[8], v[10], c2e, s2e);  ROTP(v[9], v[11], c2e, s2e);
        // t3: local pairs (0,1),(2,3) re & im
        ROTP(v[0], v[1],  c3x, s3x);  ROTP(v[2], v[3],   c3y, s3y);
        ROTP(v[8], v[9],  c3x, s3x);  ROTP(v[10], v[11], c3y, s3y);

        // ---- B fragments: slots ARE the lane's own amps -> pure cvt ----
        H8 b0, b1;
        b0.h2[0] = __builtin_amdgcn_cvt_pkrtz(v[0],  v[1]);
        b0.h2[1] = __builtin_amdgcn_cvt_pkrtz(v[2],  v[3]);
        b0.h2[2] = __builtin_amdgcn_cvt_pkrtz(v[4],  v[5]);
        b0.h2[3] = __builtin_amdgcn_cvt_pkrtz(v[6],  v[7]);
        b1.h2[0] = __builtin_amdgcn_cvt_pkrtz(v[8],  v[9]);
        b1.h2[1] = __builtin_amdgcn_cvt_pkrtz(v[10], v[11]);
        b1.h2[2] = __builtin_amdgcn_cvt_pkrtz(v[12], v[13]);
        b1.h2[3] = __builtin_amdgcn_cvt_pkrtz(v[14], v[15]);

        // ---- U apply: 2 chained MFMAs (K=32), fp32 accumulate ----
        f32x16 acc;
        #pragma unroll
        for (int i = 0; i < 16; ++i) acc[i] = 0.f;
        acc = __builtin_amdgcn_mfma_f32_32x32x16_f16(A0, b0.h8, acc, 0, 0, 0);
        acc = __builtin_amdgcn_mfma_f32_32x32x16_f16(A1, b1.h8, acc, 0, 0, 0);
        #pragma unroll
        for (int i = 0; i < 16; ++i) v[i] = acc[i];
    }

    // ---- probabilities -> clipped output, (b, 16, 64, 64) ----
    float* ob = out + (size_t)b * 65536 + (size_t)row * 64 + xc;
    #pragma unroll
    for (int k = 0; k < 4; ++k) {
        const float plo = v[k]   * v[k]   + v[8+k]  * v[8+k];   // amp 4hi+k
        const float phi = v[4+k] * v[4+k] + v[12+k] * v[12+k];  // amp 8+4hi+k
        ob[(4*hi + k) * 4096]     = fminf(plo * 8.f, 1.f);
        ob[(8 + 4*hi + k) * 4096] = fminf(phi * 8.f, 1.f);
    }
}

extern "C" void kernel_launch(void* const* d_in, const int* in_sizes, int n_in,
                              void* d_out, int out_size, void* d_ws, size_t ws_size,
                              hipStream_t stream) {
    const float* x   = (const float*)d_in[0];
    const float* wts = (const float*)d_in[1];
    float* out = (float*)d_out;
    // 131072 pixels, 2 lanes each: 1024 blocks x 256 threads
    qconv_kernel<<<1024, 256, 0, stream>>>(x, wts, out);
}

// Round 12
// 14.833 us; speedup vs baseline: 1.3598x; 1.1088x over previous
//
#include <hip/hip_runtime.h>

// ---------------------------------------------------------------------------
// Quantum conv2d, MFMA edition v3 (packed-fp32 cascade).
// Row/K convention (validated R8: any consistent A/B convention cancels HW
// k-wiring): matrix row 2m = Re(amp), row 2m+1 = Im(amp); K slot 2n = Re,
// 2n+1 = Im. Consequence: MFMA acc register pairs (2j,2j+1) = (Re,Im) of one
// amplitude -> state is f2[8] (union with f32x16, zero repack), the entire
// Mottonen cascade runs on v_pk_fma_f32, and B-pack is cvt_pkrtz(re,im).
// Lane half h owns amps alpha(h,j) = j<4 ? 4h+j : 4h+j+4  (j=0..7).
// ---------------------------------------------------------------------------

typedef float     f2      __attribute__((ext_vector_type(2)));
typedef __fp16    fp16x2  __attribute__((ext_vector_type(2)));
typedef _Float16  half8_t __attribute__((ext_vector_type(8)));
typedef float     f32x16  __attribute__((ext_vector_type(16)));

union H8  { fp16x2 h2[4]; half8_t h8; };
union AccW { f32x16 a; f2 w[8]; };

// ---------- f2 complex helpers (setup phase: evolve U columns) ----------
__device__ __forceinline__ f2 pkfma(f2 a, f2 b, f2 c) {
    return __builtin_elementwise_fma(a, b, c);
}
__device__ __forceinline__ f2 swap2(f2 v) {
    return __builtin_shufflevector(v, v, 1, 0);
}

struct GateM { f2 m00rr, m00ni, m01rr, m01ni, m10rr, m10ni, m11rr, m11ni; };

__device__ __forceinline__ GateM load_gate(const float* gp) {
    const float4* p = (const float4*)gp;
    const float4 e0 = p[0], e1 = p[1], e2 = p[2], e3 = p[3];
    GateM G;
    G.m00rr = f2{e0.x, e0.y}; G.m00ni = f2{e0.z, e0.w};
    G.m01rr = f2{e1.x, e1.y}; G.m01ni = f2{e1.z, e1.w};
    G.m10rr = f2{e2.x, e2.y}; G.m10ni = f2{e2.z, e2.w};
    G.m11rr = f2{e3.x, e3.y}; G.m11ni = f2{e3.z, e3.w};
    return G;
}

template<int STRIDE>
__device__ __forceinline__ void apply_gate(f2* s, const GateM G) {
    #pragma unroll
    for (int m0 = 0; m0 < 16; ++m0) {
        if (m0 & STRIDE) continue;
        const int m1 = m0 | STRIDE;
        const f2 a = s[m0], b = s[m1];
        const f2 as = swap2(a), bs = swap2(b);
        f2 o0 = G.m00rr * a;
        o0 = pkfma(G.m00ni, as, o0);
        o0 = pkfma(G.m01rr, b,  o0);
        o0 = pkfma(G.m01ni, bs, o0);
        f2 o1 = G.m10rr * a;
        o1 = pkfma(G.m10ni, as, o1);
        o1 = pkfma(G.m11rr, b,  o1);
        o1 = pkfma(G.m11ni, bs, o1);
        s[m0] = o0; s[m1] = o1;
    }
}

template<int BC, int BT>
__device__ __forceinline__ void apply_cnot(f2* s) {
    #pragma unroll
    for (int m = 0; m < 16; ++m) {
        if ((m & BC) && !(m & BT)) {
            const int m2 = m | BT;
            const f2 t = s[m]; s[m] = s[m2]; s[m2] = t;
        }
    }
}

// Branch-free multiplexed-RY node: lo+=1e-30 makes lo=hi=0 -> (c,s)=(1,0).
__device__ __forceinline__ void node_cs(float lo, float hi_, float& c, float& s) {
    const float lo2 = lo + 1e-30f;
    const float r = __builtin_amdgcn_rsqf(lo2 + hi_);
    c = __builtin_amdgcn_sqrtf(lo2) * r;
    s = __builtin_amdgcn_sqrtf(hi_) * r;
}

// Packed rotation on (re,im) pairs: a' = c*a - s*b ; b' = s*a + c*b
#define PKROT(a, b, cc, ss) { \
    const f2 _na = __builtin_elementwise_fma(cc, a, -((ss) * (b))); \
    const f2 _nb = __builtin_elementwise_fma(ss, a,  ((cc) * (b))); \
    (a) = _na; (b) = _nb; }

__global__ __launch_bounds__(256, 4) void qconv_kernel(
        const float* __restrict__ x,     // (32, 4, 64, 64)
        const float* __restrict__ wts,   // (4, 2, 4, 3)
        float* __restrict__ out) {       // (32, 16, 64, 64)
    __shared__ float   smat[32 * 16];    // 2 KB packed gate coeffs
    __shared__ float   tile[4 * 4 * 64]; // 4 KB input rows 2ry-1..2ry+2
    __shared__ f2      ucol[4 * 16 * 16];// 8 KB U columns (complex f32)
    __shared__ half8_t ufrag[4 * 2 * 64];// 4 KB A-fragments [ch][mfma][lane]

    const int tid = threadIdx.x;
    const int blk = blockIdx.x;          // 1024 blocks
    const int b  = blk >> 5;             // image
    const int ry = blk & 31;             // rows 2ry, 2ry+1

    // --- stage input tile (coalesced), pad with 0.01 ---
    const float* xb = x + (size_t)b * 16384;
    #pragma unroll
    for (int i = 0; i < 4; ++i) {
        const int e = tid + i * 256;     // [r][ch][col], r=0..3
        const int r = e >> 8, ch = (e >> 6) & 3, col = e & 63;
        const int gy = 2 * ry - 1 + r;
        const int gyc = min(max(gy, 0), 63);
        float val = xb[ch * 4096 + gyc * 64 + col];
        val = ((unsigned)gy < 64u) ? val : 0.01f;
        tile[e] = val;
    }

    // --- build packed Rot matrices (one thread per gate) ---
    if (tid < 32) {
        const float phi   = wts[tid*3 + 0];
        const float theta = wts[tid*3 + 1];
        const float omega = wts[tid*3 + 2];
        float st, ct; __sincosf(0.5f * theta,         &st, &ct);
        float sA, cA; __sincosf(0.5f * (phi + omega), &sA, &cA);
        float sB, cB; __sincosf(0.5f * (phi - omega), &sB, &cB);
        float* g = &smat[tid * 16];
        g[0]  =  cA*ct; g[1]  =  cA*ct; g[2]  =  sA*ct; g[3]  = -sA*ct; // m00
        g[4]  = -cB*st; g[5]  = -cB*st; g[6]  =  sB*st; g[7]  = -sB*st; // m01
        g[8]  =  cB*st; g[9]  =  cB*st; g[10] =  sB*st; g[11] = -sB*st; // m10
        g[12] =  cA*ct; g[13] =  cA*ct; g[14] = -sA*ct; g[15] =  sA*ct; // m11
    }
    __syncthreads();

    // --- evolve U columns: thread t<64 owns (ch = t>>4, col = t&15) ---
    if (tid < 64) {
        const int ch = tid >> 4, col = tid & 15;
        f2 u[16];
        #pragma unroll
        for (int j = 0; j < 16; ++j)
            u[j] = (j == col) ? f2{1.f, 0.f} : f2{0.f, 0.f};
        const float* cb = smat + ch * 128;
        apply_gate<8>(u, load_gate(cb + 0*16));
        apply_gate<4>(u, load_gate(cb + 1*16));
        apply_gate<2>(u, load_gate(cb + 2*16));
        apply_gate<1>(u, load_gate(cb + 3*16));
        apply_cnot<8, 4>(u); apply_cnot<4, 2>(u);
        apply_cnot<2, 1>(u); apply_cnot<1, 8>(u);
        apply_gate<8>(u, load_gate(cb + 4*16));
        apply_gate<4>(u, load_gate(cb + 5*16));
        apply_gate<2>(u, load_gate(cb + 6*16));
        apply_gate<1>(u, load_gate(cb + 7*16));
        apply_cnot<8, 2>(u); apply_cnot<4, 1>(u);
        apply_cnot<2, 8>(u); apply_cnot<1, 4>(u);
        #pragma unroll
        for (int j = 0; j < 16; ++j)
            ucol[(ch * 16 + col) * 16 + j] = u[j];   // ucol[ch][in][out]
    }
    __syncthreads();

    // --- build A-fragments with interleaved (Re,Im) row/K convention ---
    {
        const int ch = tid >> 6, l = tid & 63;
        const int mrow = l & 31, kf = l >> 5;
        // row -> (hi_r, j, part): i = (r&3)|((r>>3)<<2); j=i>>1; part=i&1
        const int hr = (mrow >> 2) & 1;
        const int ii = (mrow & 3) | ((mrow >> 3) << 2);
        const int jj = ii >> 1, pr = ii & 1;
        const int amp_out = (jj < 4) ? 4*hr + jj : 4*hr + jj + 4;
        #pragma unroll
        for (int m = 0; m < 2; ++m) {
            half8_t f;
            #pragma unroll
            for (int i = 0; i < 8; ++i) {
                const int n = i >> 1, pk = i & 1;
                const int jin = 4*m + n;
                const int amp_in = (jin < 4) ? 4*kf + jin : 4*kf + jin + 4;
                const f2 e = ucol[(ch * 16 + amp_in) * 16 + amp_out];
                // (Re-out,Re-in)=Ur  (Re,Im)=-Ui  (Im,Re)=Ui  (Im,Im)=Ur
                const float val = pr ? (pk ? e.x : e.y) : (pk ? -e.y : e.x);
                f[i] = (_Float16)val;
            }
            ufrag[(ch * 2 + m) * 64 + l] = f;
        }
    }
    __syncthreads();

    // --- main: wave w (0-3) -> row 2ry+(w>>1), cols 32*(w&1)+..; 2 lanes/px ---
    const int wv = tid >> 6, lane = tid & 63;
    const int hi = lane >> 5;                 // amp-half this lane owns
    const int row = 2 * ry + (wv >> 1);
    const int xc = ((wv & 1) << 5) + (lane & 31);
    const int colm = min(max(xc - 1, 0), 63);
    const int colp = min(xc + 1, 63);
    const bool inm = xc > 0, inp = xc < 63;
    const int tr0 = (wv >> 1);                // tile row base for dy=0

    // state: S.w[j] = (Re, Im) of amp alpha(hi, j)
    AccW S;
    #pragma unroll
    for (int j = 0; j < 8; ++j) S.w[j] = f2{0.f, 0.f};
    S.w[0].x = hi ? 0.f : 1.f;                // |0>

    #pragma unroll
    for (int ic = 0; ic < 4; ++ic) {
        // ---- A fragments early: ds_read_b128 latency hides under cascade ----
        const half8_t A0 = ufrag[(ic * 2 + 0) * 64 + lane];
        const half8_t A1 = ufrag[(ic * 2 + 1) * 64 + lane];

        // ---- squared 3x3 patch ----
        float q[9];
        #pragma unroll
        for (int dy = 0; dy < 3; ++dy) {
            const float* rowp = tile + ((tr0 + dy) * 4 + ic) * 64;
            float vm = rowp[colm]; vm = inm ? vm : 0.01f;
            float v0 = rowp[xc];
            float vp = rowp[colp]; vp = inp ? vp : 0.01f;
            q[dy*3 + 0] = vm * vm;
            q[dy*3 + 1] = v0 * v0;
            q[dy*3 + 2] = vp * vp;
        }

        // ---- Mottonen nodes: the 5 this lane-half needs ----
        const float s01 = q[0]+q[1], s23 = q[2]+q[3];
        const float s45 = q[4]+q[5], s67 = q[6]+q[7];
        const float s03 = s01+s23, s47 = s45+s67, s07 = s03+s47;
        const float i2lo = hi ? s45  : s01,  i2hi = hi ? s67  : s23;
        const float i3xl = hi ? q[4] : q[0], i3xh = hi ? q[5] : q[1];
        const float i3yl = hi ? q[6] : q[2], i3yh = hi ? q[7] : q[3];
        float c0,s0,c1,s1,c2e,s2e,c3x,s3x,c3y,s3y;
        node_cs(s07,  q[8], c0,  s0);
        node_cs(s03,  s47,  c1,  s1);
        node_cs(i2lo, i2hi, c2e, s2e);
        node_cs(i3xl, i3xh, c3x, s3x);
        node_cs(i3yl, i3yh, c3y, s3y);
        const float bs1 = hi ? s1 : -s1;

        // broadcast to packed coeffs
        const f2 c0f = f2{c0, c0},   s0f = f2{s0, s0};
        const f2 c1f = f2{c1, c1},   b1f = f2{bs1, bs1};
        const f2 c2f = f2{c2e, c2e}, s2f = f2{s2e, s2e};
        const f2 c3xf = f2{c3x, c3x}, s3xf = f2{s3x, s3x};
        const f2 c3yf = f2{c3y, c3y}, s3yf = f2{s3y, s3y};

        // ---- cascade, fully packed ----
        // t0: amps (a, a+8) = (w[j], w[j+4])
        PKROT(S.w[0], S.w[4], c0f, s0f);
        PKROT(S.w[1], S.w[5], c0f, s0f);
        PKROT(S.w[2], S.w[6], c0f, s0f);
        PKROT(S.w[3], S.w[7], c0f, s0f);
        // t1: amps (a, a+4) cross-lane on w[0..3]; b=1 block is identity
        f2 p[4];
        #pragma unroll
        for (int j = 0; j < 4; ++j) {
            p[j].x = __shfl_xor(S.w[j].x, 32);
            p[j].y = __shfl_xor(S.w[j].y, 32);
        }
        #pragma unroll
        for (int j = 0; j < 4; ++j)
            S.w[j] = __builtin_elementwise_fma(c1f, S.w[j], b1f * p[j]);
        // t2: (w0,w2),(w1,w3); b=2,3 identity
        PKROT(S.w[0], S.w[2], c2f, s2f);
        PKROT(S.w[1], S.w[3], c2f, s2f);
        // t3: (w0,w1),(w2,w3); b=4..7 identity
        PKROT(S.w[0], S.w[1], c3xf, s3xf);
        PKROT(S.w[2], S.w[3], c3yf, s3yf);

        // ---- B fragments: (re,im) interleaved K slots, lane-local ----
        H8 b0, b1;
        #pragma unroll
        for (int n = 0; n < 4; ++n) {
            b0.h2[n] = __builtin_amdgcn_cvt_pkrtz(S.w[n].x,     S.w[n].y);
            b1.h2[n] = __builtin_amdgcn_cvt_pkrtz(S.w[4 + n].x, S.w[4 + n].y);
        }

        // ---- U apply: 2 chained MFMAs (K=32), fp32 accumulate ----
        f32x16 acc;
        #pragma unroll
        for (int i = 0; i < 16; ++i) acc[i] = 0.f;
        acc = __builtin_amdgcn_mfma_f32_32x32x16_f16(A0, b0.h8, acc, 0, 0, 0);
        acc = __builtin_amdgcn_mfma_f32_32x32x16_f16(A1, b1.h8, acc, 0, 0, 0);
        S.a = acc;
    }

    // ---- probabilities -> clipped output, (b, 16, 64, 64) ----
    float* ob = out + (size_t)b * 65536 + (size_t)row * 64 + xc;
    #pragma unroll
    for (int j = 0; j < 8; ++j) {
        const int amp = (j < 4) ? 4*hi + j : 4*hi + j + 4;
        const float pr = S.w[j].x * S.w[j].x + S.w[j].y * S.w[j].y;
        ob[amp * 4096] = fminf(pr * 8.f, 1.f);
    }
}

extern "C" void kernel_launch(void* const* d_in, const int* in_sizes, int n_in,
                              void* d_out, int out_size, void* d_ws, size_t ws_size,
                              hipStream_t stream) {
    const float* x   = (const float*)d_in[0];
    const float* wts = (const float*)d_in[1];
    float* out = (float*)d_out;
    // 131072 pixels, 2 lanes each: 1024 blocks x 256 threads
    qconv_kernel<<<1024, 256, 0, stream>>>(x, wts, out);
}

// Round 13
// 14.144 us; speedup vs baseline: 1.4260x; 1.0487x over previous
//
#include <hip/hip_runtime.h>

// ---------------------------------------------------------------------------
// Quantum conv2d, MFMA edition v4 (rsq-only Mottonen coefficients).
// Row/K convention (validated R8): row 2m = Re(amp), 2m+1 = Im(amp); K slot
// 2n = Re, 2n+1 = Im -> MFMA acc pairs are (Re,Im) of one amp, state = f2[8],
// cascade fully on v_pk_fma_f32, B-pack = cvt_pkrtz(re,im).
// New in v4: node coefficients need ZERO v_sqrt. Inputs are >= 0, so
// sqrt(q_j) = x_j (raw patch value), and interior sqrt(s) = s * rsq(s) where
// the rsq is already needed as a child node's denominator. 6 rsq/channel
// replaces 15 transcendentals.
// ---------------------------------------------------------------------------

typedef float     f2      __attribute__((ext_vector_type(2)));
typedef __fp16    fp16x2  __attribute__((ext_vector_type(2)));
typedef _Float16  half8_t __attribute__((ext_vector_type(8)));
typedef float     f32x16  __attribute__((ext_vector_type(16)));

union H8   { fp16x2 h2[4]; half8_t h8; };
union AccW { f32x16 a; f2 w[8]; };

// ---------- f2 complex helpers (setup phase: evolve U columns) ----------
__device__ __forceinline__ f2 pkfma(f2 a, f2 b, f2 c) {
    return __builtin_elementwise_fma(a, b, c);
}
__device__ __forceinline__ f2 swap2(f2 v) {
    return __builtin_shufflevector(v, v, 1, 0);
}

struct GateM { f2 m00rr, m00ni, m01rr, m01ni, m10rr, m10ni, m11rr, m11ni; };

__device__ __forceinline__ GateM load_gate(const float* gp) {
    const float4* p = (const float4*)gp;
    const float4 e0 = p[0], e1 = p[1], e2 = p[2], e3 = p[3];
    GateM G;
    G.m00rr = f2{e0.x, e0.y}; G.m00ni = f2{e0.z, e0.w};
    G.m01rr = f2{e1.x, e1.y}; G.m01ni = f2{e1.z, e1.w};
    G.m10rr = f2{e2.x, e2.y}; G.m10ni = f2{e2.z, e2.w};
    G.m11rr = f2{e3.x, e3.y}; G.m11ni = f2{e3.z, e3.w};
    return G;
}

template<int STRIDE>
__device__ __forceinline__ void apply_gate(f2* s, const GateM G) {
    #pragma unroll
    for (int m0 = 0; m0 < 16; ++m0) {
        if (m0 & STRIDE) continue;
        const int m1 = m0 | STRIDE;
        const f2 a = s[m0], b = s[m1];
        const f2 as = swap2(a), bs = swap2(b);
        f2 o0 = G.m00rr * a;
        o0 = pkfma(G.m00ni, as, o0);
        o0 = pkfma(G.m01rr, b,  o0);
        o0 = pkfma(G.m01ni, bs, o0);
        f2 o1 = G.m10rr * a;
        o1 = pkfma(G.m10ni, as, o1);
        o1 = pkfma(G.m11rr, b,  o1);
        o1 = pkfma(G.m11ni, bs, o1);
        s[m0] = o0; s[m1] = o1;
    }
}

template<int BC, int BT>
__device__ __forceinline__ void apply_cnot(f2* s) {
    #pragma unroll
    for (int m = 0; m < 16; ++m) {
        if ((m & BC) && !(m & BT)) {
            const int m2 = m | BT;
            const f2 t = s[m]; s[m] = s[m2]; s[m2] = t;
        }
    }
}

// Packed rotation on (re,im) pairs: a' = c*a - s*b ; b' = s*a + c*b
#define PKROT(a, b, cc, ss) { \
    const f2 _na = __builtin_elementwise_fma(cc, a, -((ss) * (b))); \
    const f2 _nb = __builtin_elementwise_fma(ss, a,  ((cc) * (b))); \
    (a) = _na; (b) = _nb; }

__global__ __launch_bounds__(256, 4) void qconv_kernel(
        const float* __restrict__ x,     // (32, 4, 64, 64)
        const float* __restrict__ wts,   // (4, 2, 4, 3)
        float* __restrict__ out) {       // (32, 16, 64, 64)
    __shared__ float   smat[32 * 16];    // 2 KB packed gate coeffs
    __shared__ float   tile[4 * 4 * 64]; // 4 KB input rows 2ry-1..2ry+2
    __shared__ f2      ucol[4 * 16 * 16];// 8 KB U columns (complex f32)
    __shared__ half8_t ufrag[4 * 2 * 64];// 4 KB A-fragments [ch][mfma][lane]

    const int tid = threadIdx.x;
    const int blk = blockIdx.x;          // 1024 blocks
    const int b  = blk >> 5;             // image
    const int ry = blk & 31;             // rows 2ry, 2ry+1

    // --- stage input tile (coalesced), pad with 0.01 ---
    const float* xb = x + (size_t)b * 16384;
    #pragma unroll
    for (int i = 0; i < 4; ++i) {
        const int e = tid + i * 256;     // [r][ch][col], r=0..3
        const int r = e >> 8, ch = (e >> 6) & 3, col = e & 63;
        const int gy = 2 * ry - 1 + r;
        const int gyc = min(max(gy, 0), 63);
        float val = xb[ch * 4096 + gyc * 64 + col];
        val = ((unsigned)gy < 64u) ? val : 0.01f;
        tile[e] = val;
    }

    // --- build packed Rot matrices (one thread per gate) ---
    if (tid < 32) {
        const float phi   = wts[tid*3 + 0];
        const float theta = wts[tid*3 + 1];
        const float omega = wts[tid*3 + 2];
        float st, ct; __sincosf(0.5f * theta,         &st, &ct);
        float sA, cA; __sincosf(0.5f * (phi + omega), &sA, &cA);
        float sB, cB; __sincosf(0.5f * (phi - omega), &sB, &cB);
        float* g = &smat[tid * 16];
        g[0]  =  cA*ct; g[1]  =  cA*ct; g[2]  =  sA*ct; g[3]  = -sA*ct; // m00
        g[4]  = -cB*st; g[5]  = -cB*st; g[6]  =  sB*st; g[7]  = -sB*st; // m01
        g[8]  =  cB*st; g[9]  =  cB*st; g[10] =  sB*st; g[11] = -sB*st; // m10
        g[12] =  cA*ct; g[13] =  cA*ct; g[14] = -sA*ct; g[15] =  sA*ct; // m11
    }
    __syncthreads();

    // --- evolve U columns: thread t<64 owns (ch = t>>4, col = t&15) ---
    if (tid < 64) {
        const int ch = tid >> 4, col = tid & 15;
        f2 u[16];
        #pragma unroll
        for (int j = 0; j < 16; ++j)
            u[j] = (j == col) ? f2{1.f, 0.f} : f2{0.f, 0.f};
        const float* cb = smat + ch * 128;
        apply_gate<8>(u, load_gate(cb + 0*16));
        apply_gate<4>(u, load_gate(cb + 1*16));
        apply_gate<2>(u, load_gate(cb + 2*16));
        apply_gate<1>(u, load_gate(cb + 3*16));
        apply_cnot<8, 4>(u); apply_cnot<4, 2>(u);
        apply_cnot<2, 1>(u); apply_cnot<1, 8>(u);
        apply_gate<8>(u, load_gate(cb + 4*16));
        apply_gate<4>(u, load_gate(cb + 5*16));
        apply_gate<2>(u, load_gate(cb + 6*16));
        apply_gate<1>(u, load_gate(cb + 7*16));
        apply_cnot<8, 2>(u); apply_cnot<4, 1>(u);
        apply_cnot<2, 8>(u); apply_cnot<1, 4>(u);
        #pragma unroll
        for (int j = 0; j < 16; ++j)
            ucol[(ch * 16 + col) * 16 + j] = u[j];   // ucol[ch][in][out]
    }
    __syncthreads();

    // --- build A-fragments with interleaved (Re,Im) row/K convention ---
    {
        const int ch = tid >> 6, l = tid & 63;
        const int mrow = l & 31, kf = l >> 5;
        const int hr = (mrow >> 2) & 1;
        const int ii = (mrow & 3) | ((mrow >> 3) << 2);
        const int jj = ii >> 1, pr = ii & 1;
        const int amp_out = (jj < 4) ? 4*hr + jj : 4*hr + jj + 4;
        #pragma unroll
        for (int m = 0; m < 2; ++m) {
            half8_t f;
            #pragma unroll
            for (int i = 0; i < 8; ++i) {
                const int n = i >> 1, pk = i & 1;
                const int jin = 4*m + n;
                const int amp_in = (jin < 4) ? 4*kf + jin : 4*kf + jin + 4;
                const f2 e = ucol[(ch * 16 + amp_in) * 16 + amp_out];
                const float val = pr ? (pk ? e.x : e.y) : (pk ? -e.y : e.x);
                f[i] = (_Float16)val;
            }
            ufrag[(ch * 2 + m) * 64 + l] = f;
        }
    }
    __syncthreads();

    // --- main: wave w (0-3) -> row 2ry+(w>>1), cols 32*(w&1)+..; 2 lanes/px ---
    const int wv = tid >> 6, lane = tid & 63;
    const int hi = lane >> 5;                 // amp-half this lane owns
    const int row = 2 * ry + (wv >> 1);
    const int xc = ((wv & 1) << 5) + (lane & 31);
    const int colm = min(max(xc - 1, 0), 63);
    const int colp = min(xc + 1, 63);
    const bool inm = xc > 0, inp = xc < 63;
    const int tr0 = (wv >> 1);                // tile row base for dy=0

    // state: S.w[j] = (Re, Im) of amp alpha(hi, j)
    AccW S;
    #pragma unroll
    for (int j = 0; j < 8; ++j) S.w[j] = f2{0.f, 0.f};
    S.w[0].x = hi ? 0.f : 1.f;                // |0>

    constexpr float EPS = 1e-30f;

    #pragma unroll
    for (int ic = 0; ic < 4; ++ic) {
        // ---- A fragments early: ds_read_b128 latency hides under cascade ----
        const half8_t A0 = ufrag[(ic * 2 + 0) * 64 + lane];
        const half8_t A1 = ufrag[(ic * 2 + 1) * 64 + lane];

        // ---- raw 3x3 patch (values >= 0: sqrt(q_j) == xv[j]) ----
        float xv[9];
        #pragma unroll
        for (int dy = 0; dy < 3; ++dy) {
            const float* rowp = tile + ((tr0 + dy) * 4 + ic) * 64;
            float vm = rowp[colm]; vm = inm ? vm : 0.01f;
            float v0 = rowp[xc];
            float vp = rowp[colp]; vp = inp ? vp : 0.01f;
            xv[dy*3 + 0] = vm;
            xv[dy*3 + 1] = v0;
            xv[dy*3 + 2] = vp;
        }

        // ---- pairwise sums of squares ----
        const float s01 = fmaf(xv[0], xv[0], xv[1]*xv[1]);
        const float s23 = fmaf(xv[2], xv[2], xv[3]*xv[3]);
        const float s45 = fmaf(xv[4], xv[4], xv[5]*xv[5]);
        const float s67 = fmaf(xv[6], xv[6], xv[7]*xv[7]);
        const float s03 = s01 + s23, s47 = s45 + s67, s07 = s03 + s47;
        const float Sf  = fmaf(xv[8], xv[8], s07);

        // ---- per-half raw/sum selection ----
        const float a_  = hi ? xv[4] : xv[0], b_  = hi ? xv[5] : xv[1];
        const float c_  = hi ? xv[6] : xv[2], d_  = hi ? xv[7] : xv[3];
        const float sab = hi ? s45 : s01,     scd = hi ? s67 : s23;

        // ---- 6 rsq, ZERO sqrt ----
        const float rAB = __builtin_amdgcn_rsqf(sab + EPS);
        const float rCD = __builtin_amdgcn_rsqf(scd + EPS);
        const float r03 = __builtin_amdgcn_rsqf(s03 + EPS);
        const float r47 = __builtin_amdgcn_rsqf(s47 + EPS);
        const float r07 = __builtin_amdgcn_rsqf(s07 + EPS);
        const float rS  = __builtin_amdgcn_rsqf(Sf  + EPS);
        const float rS4 = hi ? r47 : r03;

        // ---- node coefficients via telescoped products ----
        const float c0  = s07 * r07 * rS,   s0  = xv[8] * rS;
        const float c1  = s03 * r03 * r07,  s1v = s47 * r47 * r07;
        const float c2e = sab * rAB * rS4,  s2e = scd * rCD * rS4;
        const float c3x = a_ * rAB,         s3x = b_ * rAB;
        const float c3y = c_ * rCD,         s3y = d_ * rCD;
        const float bs1 = hi ? s1v : -s1v;

        // broadcast to packed coeffs
        const f2 c0f = f2{c0, c0},   s0f = f2{s0, s0};
        const f2 c1f = f2{c1, c1},   b1f = f2{bs1, bs1};
        const f2 c2f = f2{c2e, c2e}, s2f = f2{s2e, s2e};
        const f2 c3xf = f2{c3x, c3x}, s3xf = f2{s3x, s3x};
        const f2 c3yf = f2{c3y, c3y}, s3yf = f2{s3y, s3y};

        // ---- cascade, fully packed ----
        PKROT(S.w[0], S.w[4], c0f, s0f);
        PKROT(S.w[1], S.w[5], c0f, s0f);
        PKROT(S.w[2], S.w[6], c0f, s0f);
        PKROT(S.w[3], S.w[7], c0f, s0f);
        // t1: cross-lane (xor32) on w[0..3]; b=1 block identity
        f2 p[4];
        #pragma unroll
        for (int j = 0; j < 4; ++j) {
            p[j].x = __shfl_xor(S.w[j].x, 32);
            p[j].y = __shfl_xor(S.w[j].y, 32);
        }
        #pragma unroll
        for (int j = 0; j < 4; ++j)
            S.w[j] = __builtin_elementwise_fma(c1f, S.w[j], b1f * p[j]);
        PKROT(S.w[0], S.w[2], c2f, s2f);
        PKROT(S.w[1], S.w[3], c2f, s2f);
        PKROT(S.w[0], S.w[1], c3xf, s3xf);
        PKROT(S.w[2], S.w[3], c3yf, s3yf);

        // ---- B fragments: (re,im) interleaved K slots, lane-local ----
        H8 b0, b1;
        #pragma unroll
        for (int n = 0; n < 4; ++n) {
            b0.h2[n] = __builtin_amdgcn_cvt_pkrtz(S.w[n].x,     S.w[n].y);
            b1.h2[n] = __builtin_amdgcn_cvt_pkrtz(S.w[4 + n].x, S.w[4 + n].y);
        }

        // ---- U apply: 2 chained MFMAs (K=32), fp32 accumulate ----
        f32x16 acc;
        #pragma unroll
        for (int i = 0; i < 16; ++i) acc[i] = 0.f;
        acc = __builtin_amdgcn_mfma_f32_32x32x16_f16(A0, b0.h8, acc, 0, 0, 0);
        acc = __builtin_amdgcn_mfma_f32_32x32x16_f16(A1, b1.h8, acc, 0, 0, 0);
        S.a = acc;
    }

    // ---- probabilities -> clipped output, (b, 16, 64, 64) ----
    float* ob = out + (size_t)b * 65536 + (size_t)row * 64 + xc;
    #pragma unroll
    for (int j = 0; j < 8; ++j) {
        const int amp = (j < 4) ? 4*hi + j : 4*hi + j + 4;
        const float pr = S.w[j].x * S.w[j].x + S.w[j].y * S.w[j].y;
        ob[amp * 4096] = fminf(pr * 8.f, 1.f);
    }
}

extern "C" void kernel_launch(void* const* d_in, const int* in_sizes, int n_in,
                              void* d_out, int out_size, void* d_ws, size_t ws_size,
                              hipStream_t stream) {
    const float* x   = (const float*)d_in[0];
    const float* wts = (const float*)d_in[1];
    float* out = (float*)d_out;
    // 131072 pixels, 2 lanes each: 1024 blocks x 256 threads
    qconv_kernel<<<1024, 256, 0, stream>>>(x, wts, out);
}